// Round 7
// baseline (297.444 us; speedup 1.0000x reference)
//
#include <hip/hip_runtime.h>
#include <hip/hip_bf16.h>

#define NQ 4096
#define NK 8192
#define DQK 256
#define DA 64
#define NH 4
#define DOUT 256
#define NQT (NQ / 32)        // 128 q-tiles of 32
#define NSUP 8               // surviving partials per (h,qt): 8 key-regions
#define LOG2E 1.44269504088896340736f
#define QSCALE (0.125f * LOG2E)   // 1/sqrt(64) * log2(e), folded into Qp

typedef __attribute__((ext_vector_type(8))) short bf16x8;
typedef __attribute__((ext_vector_type(4))) float f32x4;
typedef __attribute__((ext_vector_type(2))) _Float16 f16x2;
typedef __attribute__((ext_vector_type(4))) _Float16 f16x4;
typedef __attribute__((ext_vector_type(8))) _Float16 f16x8;

__device__ inline unsigned short f2bf(float f) {
  union { float f; unsigned u; } v; v.f = f;
  unsigned r = v.u + 0x7fff + ((v.u >> 16) & 1);  // RNE
  return (unsigned short)(r >> 16);
}

__device__ inline f16x2 pkrtz(float a, float b) {
  return __builtin_bit_cast(f16x2, __builtin_amdgcn_cvt_pkrtz(a, b));
}

__device__ inline void gload16(const void* g, void* l) {
  __builtin_amdgcn_global_load_lds(
      (const __attribute__((address_space(1))) void*)g,
      (__attribute__((address_space(3))) void*)l, 16, 0, 0);
}

// ---------------------------------------------------------------------------
// 1. mask (int32 NQ x NK) -> TRANSPOSED bitmask bitsT[word32][row] (4 MB).
// ---------------------------------------------------------------------------
__global__ __launch_bounds__(256) void maskbits_kernel(
    const int* __restrict__ mask, unsigned* __restrict__ bitsT) {
  const int NW = 8192 * 4;                       // total waves
  int wid = blockIdx.x * 4 + (threadIdx.x >> 6);
  int lane = threadIdx.x & 63;
  for (int j = 0; j < 2; ++j) {
    int v[8];
#pragma unroll
    for (int u = 0; u < 8; ++u) {
      int c = wid + (j * 8 + u) * NW;   // u64 chunk id: row = c>>7, ch = c&127
      v[u] = mask[(size_t)(c >> 7) * NK + (c & 127) * 64 + lane];
    }
#pragma unroll
    for (int u = 0; u < 8; ++u) {
      unsigned long long b = __ballot(v[u] != 0);
      int c = wid + (j * 8 + u) * NW;
      int n = c >> 7, ch = c & 127;
      if (lane == 0)  bitsT[(size_t)(2 * ch) * NQ + n] = (unsigned)b;
      if (lane == 32) bitsT[(size_t)(2 * ch + 1) * NQ + n] = (unsigned)(b >> 32);
    }
  }
}

// ---------------------------------------------------------------------------
// 2. projections (unchanged).
// ---------------------------------------------------------------------------
__global__ __launch_bounds__(256) void proj_kernel(
    const float* __restrict__ xQ, const float* __restrict__ xK,
    const float* __restrict__ Wq, const float* __restrict__ Wk,
    const float* __restrict__ Wv,
    unsigned short* __restrict__ Qp, unsigned short* __restrict__ Kp,
    _Float16* __restrict__ Vf) {
  __shared__ __align__(16) unsigned short Wt[64][264];  // Wt[d][c], padded

  int b = blockIdx.x;
  int proj, h, rb;
  if (b < 128)       { proj = 0; h = b >> 5;  rb = b & 31; }
  else if (b < 384)  { proj = 1; b -= 128; h = b >> 6; rb = b & 63; }
  else               { proj = 2; b -= 384; h = b >> 6; rb = b & 63; }
  const float* x = (proj == 0) ? xQ : xK;
  const float* W = (proj == 0 ? Wq : (proj == 1 ? Wk : Wv)) + (size_t)h * 256 * 64;

  for (int i = threadIdx.x; i < 16384; i += 256)
    Wt[i & 63][i >> 6] = f2bf(W[i]);
  __syncthreads();

  int lane = threadIdx.x & 63, wv = threadIdx.x >> 6;
  int quad = lane >> 4, n16 = lane & 15;
  int r0 = rb * 128 + wv * 32;          // 32 rows per wave

  f32x4 acc[2][4];
#pragma unroll
  for (int mt = 0; mt < 2; ++mt)
#pragma unroll
    for (int nt = 0; nt < 4; ++nt)
      acc[mt][nt] = (f32x4){0.f, 0.f, 0.f, 0.f};

#pragma unroll
  for (int it = 0; it < 8; ++it) {
    const int k0 = it * 32;
    bf16x8 af[2];
#pragma unroll
    for (int mt = 0; mt < 2; ++mt) {
      const float* xp = x + (size_t)(r0 + mt * 16 + n16) * 256 + k0 + quad * 8;
      const float4 a0 = *(const float4*)xp;
      const float4 a1 = *(const float4*)(xp + 4);
      bf16x8 a;
      a[0] = (short)f2bf(a0.x); a[1] = (short)f2bf(a0.y);
      a[2] = (short)f2bf(a0.z); a[3] = (short)f2bf(a0.w);
      a[4] = (short)f2bf(a1.x); a[5] = (short)f2bf(a1.y);
      a[6] = (short)f2bf(a1.z); a[7] = (short)f2bf(a1.w);
      af[mt] = a;
    }
    bf16x8 bfr[4];
#pragma unroll
    for (int nt = 0; nt < 4; ++nt)
      bfr[nt] = *(const bf16x8*)&Wt[nt * 16 + n16][k0 + quad * 8];
#pragma unroll
    for (int mt = 0; mt < 2; ++mt)
#pragma unroll
      for (int nt = 0; nt < 4; ++nt)
        acc[mt][nt] = __builtin_amdgcn_mfma_f32_16x16x32_bf16(
            af[mt], bfr[nt], acc[mt][nt], 0, 0, 0);
  }

  if (proj < 2) {
    unsigned short* outp =
        (proj == 0 ? Qp : Kp) + (size_t)h * (size_t)(proj == 0 ? NQ : NK) * 64;
    const float sc = (proj == 0) ? QSCALE : 1.0f;
#pragma unroll
    for (int mt = 0; mt < 2; ++mt)
#pragma unroll
      for (int nt = 0; nt < 4; ++nt)
#pragma unroll
        for (int r = 0; r < 4; ++r) {
          int row = r0 + mt * 16 + quad * 4 + r;
          int col = nt * 16 + n16;
          outp[(size_t)row * 64 + col] = f2bf(acc[mt][nt][r] * sc);
        }
  } else {
    // K=32 fragment-linear V: tile = h*256 + keyblock32
    int tile = h * 256 + (r0 >> 5);
#pragma unroll
    for (int nt = 0; nt < 4; ++nt) {
      f16x8 pk;
      pk[0] = (_Float16)acc[0][nt][0]; pk[1] = (_Float16)acc[0][nt][1];
      pk[2] = (_Float16)acc[0][nt][2]; pk[3] = (_Float16)acc[0][nt][3];
      pk[4] = (_Float16)acc[1][nt][0]; pk[5] = (_Float16)acc[1][nt][1];
      pk[6] = (_Float16)acc[1][nt][2]; pk[7] = (_Float16)acc[1][nt][3];
      *(f16x8*)&Vf[(((size_t)tile * 4 + nt) * 64 + lane) * 8] = pk;
    }
  }
}

// ---------------------------------------------------------------------------
// 3. flash attention, qc=4 (wave covers 64 q-rows) + true depth-2 pipeline.
//    Block = (h, kp, 4 waves x 64 q-rows). Same 8 KB K/V LDS tile now feeds
//    2x the MFMA work -> total LDS reads and staging fetch halve.
//    Grid 512 = exactly 2 blocks/CU at __launch_bounds__(256,2).
//    Issue order per iter: stage(t+2) then bits(t+2); end-of-iter
//    s_waitcnt vmcnt(10) drains exactly stage(t+1) by FIFO position
//    (newest 10 = bits(t+1)[4] + stage(t+2)[2] + bits(t+2)[4]), leaving
//    stage(t+2) + 2 bits sets in flight across the barrier.
//    l-sum via VALU adds on the already-computed exp values (no ones-MFMA).
// ---------------------------------------------------------------------------
__global__ __launch_bounds__(256, 2) void attn_kernel(
    const unsigned short* __restrict__ Qp, const unsigned short* __restrict__ Kp,
    const _Float16* __restrict__ Vf, const unsigned* __restrict__ bitsT,
    _Float16* __restrict__ Opart, float* __restrict__ Lpart) {
  __shared__ __align__(16) char lds[3][8192];   // [buf][K 4KB | V 4KB]

  // bijective XCD swizzle (8 XCDs, 512 blocks, 64/chunk)
  int orig = blockIdx.x;
  int wgid = (orig & 7) * 64 + (orig >> 3);
  int qtg = wgid & 15;
  int combo = wgid >> 4;          // h*8 + kp: each XCD owns 4 combos, same h
  int kp = combo & 7, h = combo >> 3;

  int wv = threadIdx.x >> 6, lane = threadIdx.x & 63;
  int quad = lane >> 4, n16 = lane & 15;
  int qg = qtg * 4 + wv;          // this wave's 64-row q-group (0..63)
  int qb = qg * 64;

  // Q frags (bf16, pre-scaled by QSCALE): 4 x 16 q-rows
  bf16x8 qf[4][2];
#pragma unroll
  for (int qc = 0; qc < 4; ++qc)
#pragma unroll
    for (int c = 0; c < 2; ++c)
      qf[qc][c] = *(const bf16x8*)&Qp[((size_t)h * NQ + qb + qc * 16 + n16) * 64 +
                                      c * 32 + quad * 8];

  f32x4 o[4][4];
#pragma unroll
  for (int dt = 0; dt < 4; ++dt)
#pragma unroll
    for (int qc = 0; qc < 4; ++qc) o[dt][qc] = (f32x4){0.f, 0.f, 0.f, 0.f};
  float ls[4] = {0.f, 0.f, 0.f, 0.f};

  const char* Kreg = (const char*)(Kp + (size_t)h * NK * 64 + (size_t)kp * 1024 * 64);
  const char* Vreg = (const char*)(Vf + ((size_t)h * 256 + kp * 32) * 2048);
  const unsigned* bT = bitsT + (size_t)(kp * 32) * NQ + qb;

  // per-lane source offsets: each wave stages 2 KB of the 8 KB tile image.
  const char* sb;
  int soff[2];
  if (wv < 2) {
    sb = Kreg;
#pragma unroll
    for (int i = 0; i < 2; ++i)
      soff[i] = ((wv * 16 + n16) * 64 + i * 32 + quad * 8) * 2;
  } else {
    sb = Vreg;
#pragma unroll
    for (int i = 0; i < 2; ++i)
      soff[i] = (wv - 2) * 2048 + i * 1024 + lane * 16;
  }

  auto stage = [&](int t, int bufidx) {
    char* d = &lds[bufidx][wv * 2048];
    const char* s0 = sb + (size_t)t * 4096;
#pragma unroll
    for (int i = 0; i < 2; ++i)
      gload16(s0 + soff[i], d + i * 1024);
  };

  auto compute = [&](int buf, const unsigned (&wqa)[4]) {
    const char* Kl = lds[buf];
    const char* Vl = lds[buf] + 4096;

    bf16x8 kf[2][2];
#pragma unroll
    for (int kr = 0; kr < 2; ++kr)
#pragma unroll
      for (int c = 0; c < 2; ++c)
        kf[kr][c] = *(const bf16x8*)(Kl + (kr * 2 + c) * 1024 + lane * 16);

    f16x8 vf8[4];
#pragma unroll
    for (int dt = 0; dt < 4; ++dt)
      vf8[dt] = *(const f16x8*)(Vl + dt * 1024 + lane * 16);

#pragma unroll
    for (int qc = 0; qc < 4; ++qc) {
      // S^T = K·Q^T (bf16 K=32, pre-scaled)
      f32x4 s0 = (f32x4){0.f, 0.f, 0.f, 0.f};
      f32x4 s1 = (f32x4){0.f, 0.f, 0.f, 0.f};
      s0 = __builtin_amdgcn_mfma_f32_16x16x32_bf16(kf[0][0], qf[qc][0], s0, 0, 0, 0);
      s0 = __builtin_amdgcn_mfma_f32_16x16x32_bf16(kf[0][1], qf[qc][1], s0, 0, 0, 0);
      s1 = __builtin_amdgcn_mfma_f32_16x16x32_bf16(kf[1][0], qf[qc][0], s1, 0, 0, 0);
      s1 = __builtin_amdgcn_mfma_f32_16x16x32_bf16(kf[1][1], qf[qc][1], s1, 0, 0, 0);

      unsigned wq = wqa[qc] >> (quad * 4);
      union { f16x8 v; f16x2 h[4]; } pu;
      {
        float e0 = __builtin_amdgcn_exp2f(s0[0]);
        float e1 = __builtin_amdgcn_exp2f(s0[1]);
        float e2 = __builtin_amdgcn_exp2f(s0[2]);
        float e3 = __builtin_amdgcn_exp2f(s0[3]);
        e0 = (wq & (1u << 0)) ? e0 : 0.f;
        e1 = (wq & (1u << 1)) ? e1 : 0.f;
        e2 = (wq & (1u << 2)) ? e2 : 0.f;
        e3 = (wq & (1u << 3)) ? e3 : 0.f;
        ls[qc] += (e0 + e1) + (e2 + e3);
        pu.h[0] = pkrtz(e0, e1);
        pu.h[1] = pkrtz(e2, e3);
      }
      {
        float e0 = __builtin_amdgcn_exp2f(s1[0]);
        float e1 = __builtin_amdgcn_exp2f(s1[1]);
        float e2 = __builtin_amdgcn_exp2f(s1[2]);
        float e3 = __builtin_amdgcn_exp2f(s1[3]);
        e0 = (wq & (1u << 16)) ? e0 : 0.f;
        e1 = (wq & (1u << 17)) ? e1 : 0.f;
        e2 = (wq & (1u << 18)) ? e2 : 0.f;
        e3 = (wq & (1u << 19)) ? e3 : 0.f;
        ls[qc] += (e0 + e1) + (e2 + e3);
        pu.h[2] = pkrtz(e0, e1);
        pu.h[3] = pkrtz(e2, e3);
      }
#pragma unroll
      for (int dt = 0; dt < 4; ++dt)
        o[dt][qc] = __builtin_amdgcn_mfma_f32_16x16x32_f16(vf8[dt], pu.v,
                                                           o[dt][qc], 0, 0, 0);
    }
  };

  // ---- prologue: bits(0), stage(0), stage(1), bits(1); drain thru stage(0)
  unsigned w[3][4];
#pragma unroll
  for (int j = 0; j < 4; ++j) w[0][j] = bT[j * 16 + n16];
  stage(0, 0);
  stage(1, 1);
#pragma unroll
  for (int j = 0; j < 4; ++j) w[1][j] = bT[NQ + j * 16 + n16];
  asm volatile("s_waitcnt vmcnt(6)" ::: "memory");
  __builtin_amdgcn_sched_barrier(0);
  __builtin_amdgcn_s_barrier();

  // ---- main loop: 30 full-pipeline tiles (unroll 3 -> constant buf indices)
#pragma unroll 3
  for (int t = 0; t < 30; ++t) {
    stage(t + 2, (t + 2) % 3);
#pragma unroll
    for (int j = 0; j < 4; ++j)
      w[(t + 2) % 3][j] = bT[(size_t)(t + 2) * NQ + j * 16 + n16];
    compute(t % 3, w[t % 3]);
    // newest 10 = bits(t+2)[4] + stage(t+2)[2] + bits(t+1)[4] -> stage(t+1) done
    asm volatile("s_waitcnt vmcnt(10)" ::: "memory");
    __builtin_amdgcn_sched_barrier(0);
    __builtin_amdgcn_s_barrier();
  }
  // t = 30: no new issues; drain stage(31) (newest 4 = bits(31))
  compute(0, w[0]);
  asm volatile("s_waitcnt vmcnt(4)" ::: "memory");
  __builtin_amdgcn_sched_barrier(0);
  __builtin_amdgcn_s_barrier();
  // t = 31: compute only
  compute(1, w[1]);

  // ---- l reduction across quads, then direct per-wave store
#pragma unroll
  for (int qc = 0; qc < 4; ++qc) {
    ls[qc] += __shfl_xor(ls[qc], 16);
    ls[qc] += __shfl_xor(ls[qc], 32);
  }
#pragma unroll
  for (int qc = 0; qc < 4; ++qc) {
    int qt32 = qg * 2 + (qc >> 1);
    size_t tile = ((size_t)h * NQT + qt32) * NSUP + kp;
    int row = (qc & 1) * 16 + n16;
#pragma unroll
    for (int dt = 0; dt < 4; ++dt) {
      union { f16x4 v; f16x2 h[2]; } u;
      u.h[0] = pkrtz(o[dt][qc][0], o[dt][qc][1]);
      u.h[1] = pkrtz(o[dt][qc][2], o[dt][qc][3]);
      *(f16x4*)&Opart[(tile * 32 + row) * 64 + dt * 16 + quad * 4] = u.v;
    }
    if (quad == 0) Lpart[tile * 32 + row] = ls[qc];
  }
}

// ---------------------------------------------------------------------------
// 4. combine NSUP partials + fused gates + @Wo + bo.
//    512 blocks x 8 rows; Opart read as f16x2 (paired a) -> half the loads.
// ---------------------------------------------------------------------------
__global__ __launch_bounds__(256) void combine_kernel(
    const _Float16* __restrict__ Opart, const float* __restrict__ Lpart,
    const float* __restrict__ xQ, const float* __restrict__ Wg,
    const float* __restrict__ bg, const float* __restrict__ Wo,
    const float* __restrict__ bo, float* __restrict__ out) {
  __shared__ float comb[8][64];
  __shared__ float gred[32][8];
  __shared__ float glds[8][4];
  int nb = blockIdx.x;
  int tid = threadIdx.x;
  int row0 = nb * 8;

  // gates for this block's 8 rows x 4 heads (32 dots, 8-way split each)
  {
    int rh = tid >> 3, c = tid & 7;
    int r = rh >> 2, hh = rh & 3;
    const float* xp = xQ + (size_t)(row0 + r) * 256 + c * 32;
    const float* wp = Wg + hh * 256 + c * 32;
    float s = 0.f;
#pragma unroll
    for (int e = 0; e < 32; ++e) s = fmaf(xp[e], wp[e], s);
    gred[rh][c] = s;
  }
  __syncthreads();
  if (tid < 32) {
    float s = 0.f;
#pragma unroll
    for (int c = 0; c < 8; ++c) s += gred[tid][c];
    glds[tid >> 2][tid & 3] = 1.f / (1.f + __expf(-(s + bg[tid & 3])));
  }
  __syncthreads();

  int qt = nb >> 2, rbase = (nb & 3) * 8;
  {
    int athr = tid & 31, r = tid >> 5;      // 32 a-pairs x 8 rows
    int rl = rbase + r;
    int a0 = athr * 2;
    float c0 = 0.f, c1 = 0.f;
#pragma unroll
    for (int hh = 0; hh < NH; ++hh) {
      size_t t0 = ((size_t)hh * NQT + qt) * NSUP;
      float a0s = 0.f, a1s = 0.f, lt = 0.f;
#pragma unroll
      for (int s = 0; s < NSUP; ++s) {
        size_t t = t0 + s;
        f16x2 v = *(const f16x2*)&Opart[(t * 32 + rl) * 64 + a0];
        a0s += (float)v[0];
        a1s += (float)v[1];
        lt += Lpart[t * 32 + rl];
      }
      float g = glds[r][hh] / lt;
      c0 = fmaf(g, a0s, c0);
      c1 = fmaf(g, a1s, c1);
    }
    comb[r][a0] = c0;
    comb[r][a0 + 1] = c1;
  }
  __syncthreads();

  int j = tid;
  float accv[8];
#pragma unroll
  for (int r = 0; r < 8; ++r) accv[r] = bo[j];
  for (int aa = 0; aa < 64; ++aa) {
    float w = Wo[(size_t)aa * 256 + j];
#pragma unroll
    for (int r = 0; r < 8; ++r) accv[r] = fmaf(comb[r][aa], w, accv[r]);
  }
#pragma unroll
  for (int r = 0; r < 8; ++r)
    out[(size_t)(row0 + r) * 256 + j] = accv[r];
}

// ---------------------------------------------------------------------------
extern "C" void kernel_launch(void* const* d_in, const int* in_sizes, int n_in,
                              void* d_out, int out_size, void* d_ws, size_t ws_size,
                              hipStream_t stream) {
  const float* xQ  = (const float*)d_in[0];
  const float* xK  = (const float*)d_in[1];
  const int*   mask= (const int*)d_in[2];
  const float* Wq  = (const float*)d_in[3];
  const float* Wk  = (const float*)d_in[4];
  const float* Wv  = (const float*)d_in[5];
  const float* Wg  = (const float*)d_in[6];
  const float* bg  = (const float*)d_in[7];
  const float* Wo  = (const float*)d_in[8];
  const float* bo  = (const float*)d_in[9];
  float* out = (float*)d_out;

  char* ws = (char*)d_ws;
  unsigned short* Qp   = (unsigned short*)(ws + 0);         // 2 MB   [H][NQ][64]
  unsigned short* Kp   = (unsigned short*)(ws + 2097152);   // 4 MB   [H][NK][64]
  _Float16*       Vfp  = (_Float16*)(ws + 6291456);         // 4 MB   frag-linear
  unsigned*       bitsT= (unsigned*)(ws + 10485760);        // 4 MB   [word][row]
  float*          Lp   = (float*)(ws + 14680064);           // 512 KB (4096 tiles)
  _Float16*       Op   = (_Float16*)(ws + 15204352);        // 16.8 MB f16

  maskbits_kernel<<<dim3(8192), dim3(256), 0, stream>>>(mask, bitsT);
  proj_kernel<<<dim3(640), dim3(256), 0, stream>>>(xQ, xK, Wq, Wk, Wv, Qp, Kp, Vfp);
  attn_kernel<<<dim3(512), dim3(256), 0, stream>>>(Qp, Kp, Vfp, bitsT, Op, Lp);
  combine_kernel<<<dim3(NQ / 8), dim3(256), 0, stream>>>(Op, Lp, xQ, Wg, bg,
                                                         Wo, bo, out);
}